// Round 9
// baseline (255.822 us; speedup 1.0000x reference)
//
#include <hip/hip_runtime.h>

// HiearchicalFFTShiftModel: closed-form spectrum with EXACT emulation of the
// reference's complex64 phase quantization, + fused chain+FFT pass and two
// transpose-FFT passes over 2^24 complex points (c2r packing).
//
// Round-9: fixes round-8's failure. The c2r twiddle is e^{2pi i k/2^25}
// (N = real length 2^25), so the k-step 2^21 advances it by 1/16 revolution
// (22.5 deg), not 1/8 (45 deg) as round 8 rotated. Recurrence now uses
// cos(pi/8)/sin(pi/8). Everything else as round 8:
//  - A: one sincos + exact 22.5-deg rotation replaces 8 c2r sincos/thread.
//  - B/C: launch_bounds (256,4) for 16 waves/CU latency hiding.

constexpr float TWOPI_F = 6.28318530717958647692f;
constexpr unsigned M24 = 1u << 24;
constexpr double TPD = 6.2831853071795864769;

// th in radians: reduce mod 2*pi in DOUBLE (verified numerics), evaluate with
// native HW trig (takes REVOLUTIONS).
__device__ __forceinline__ void phase_sincos(float th, float* sn, float* cs) {
    double d = (double)th * 0.15915494309189533577;  // 1/(2*pi)
    d -= rint(d);                                    // frac in [-0.5, 0.5]
    float r = (float)d;
    *sn = __builtin_amdgcn_sinf(r);
    *cs = __builtin_amdgcn_cosf(r);
}

__device__ __forceinline__ void sincos_rev(float rev, float* sn, float* cs) {
    float r = rev - rintf(rev);
    *sn = __builtin_amdgcn_sinf(r);
    *cs = __builtin_amdgcn_cosf(r);
}

__device__ __forceinline__ float2 cmul(float2 a, float2 f) {
    return make_float2(a.x * f.x - a.y * f.y, a.x * f.y + a.y * f.x);
}
__device__ __forceinline__ float2 caddf(float2 a, float2 b) { return make_float2(a.x + b.x, a.y + b.y); }
__device__ __forceinline__ float2 csubf(float2 a, float2 b) { return make_float2(a.x - b.x, a.y - b.y); }
__device__ __forceinline__ float2 cmulw(float2 a, float c, float s) {
    return make_float2(a.x * c - a.y * s, a.x * s + a.y * c);
}

// chunked bijective XCD swizzle (nblocks divisible by 8)
__device__ __forceinline__ int xcd_swizzle(int b, int nblocks) {
    int chunk = nblocks >> 3;
    return (b & 7) * chunk + (b >> 3);
}

// c_i = (float)(2pi/(2^i+1)) — compile-time table (identical to prior c_s[i]).
__device__ __forceinline__ float c_of(int i) {
    switch (i) {
    case 0:  return (float)(TPD / 2.0);
    case 1:  return (float)(TPD / 3.0);
    case 2:  return (float)(TPD / 5.0);
    case 3:  return (float)(TPD / 9.0);
    case 4:  return (float)(TPD / 17.0);
    case 5:  return (float)(TPD / 33.0);
    case 6:  return (float)(TPD / 65.0);
    case 7:  return (float)(TPD / 129.0);
    case 8:  return (float)(TPD / 257.0);
    case 9:  return (float)(TPD / 513.0);
    case 10: return (float)(TPD / 1025.0);
    case 11: return (float)(TPD / 2049.0);
    case 12: return (float)(TPD / 4097.0);
    case 13: return (float)(TPD / 8193.0);
    case 14: return (float)(TPD / 16385.0);
    case 15: return (float)(TPD / 32769.0);
    case 16: return (float)(TPD / 65537.0);
    case 17: return (float)(TPD / 131073.0);
    case 18: return (float)(TPD / 262145.0);
    case 19: return (float)(TPD / 524289.0);
    case 20: return (float)(TPD / 1048577.0);
    case 21: return (float)(TPD / 2097153.0);
    case 22: return (float)(TPD / 4194305.0);
    case 23: return (float)(TPD / 8388609.0);
    default: return (float)(TPD / 16777217.0);
    }
}

// s_i from elements (identical float ops to prior s_s[i] init)
__device__ __forceinline__ float s_of(const float* __restrict__ el, int i) {
    float e = el[i];
    float shift1 = e * (1.0f / (float)(1u << i));   // exact (pow2 scale)
    float sh2 = 1.0f - shift1;                      // THE float32 rounding
    return sh2 * (float)(1u << i);                  // exact
}

// ---------------- in-register 16-point inverse DFT (natural in/out) ----------------
__device__ __forceinline__ void fft16_inv(float2* v) {
    const float C1 = 0.92387953251128675613f;   // cos(pi/8)
    const float S1 = 0.38268343236508977173f;   // sin(pi/8)
    const float R2 = 0.70710678118654752440f;   // sqrt(2)/2
    float2 h[16];
#pragma unroll
    for (int b = 0; b < 4; ++b) {
        float2 s02 = caddf(v[b], v[b + 8]);
        float2 d02 = csubf(v[b], v[b + 8]);
        float2 s13 = caddf(v[b + 4], v[b + 12]);
        float2 d13 = csubf(v[b + 4], v[b + 12]);
        float2 id13 = make_float2(-d13.y, d13.x);          // i*d13
        h[4 * b + 0] = caddf(s02, s13);
        h[4 * b + 1] = caddf(d02, id13);
        h[4 * b + 2] = csubf(s02, s13);
        h[4 * b + 3] = csubf(d02, id13);
    }
    h[5]  = cmulw(h[5],  C1,  S1);
    h[6]  = make_float2(R2 * (h[6].x - h[6].y),  R2 * (h[6].x + h[6].y));
    h[7]  = cmulw(h[7],  S1,  C1);
    h[9]  = make_float2(R2 * (h[9].x - h[9].y),  R2 * (h[9].x + h[9].y));
    h[10] = make_float2(-h[10].y, h[10].x);
    h[11] = cmulw(h[11], -R2, R2);
    h[13] = cmulw(h[13], S1,  C1);
    h[14] = cmulw(h[14], -R2, R2);
    h[15] = cmulw(h[15], -C1, -S1);
#pragma unroll
    for (int K1 = 0; K1 < 4; ++K1) {
        float2 a = h[K1], bb = h[4 + K1], cc = h[8 + K1], dd = h[12 + K1];
        float2 sac = caddf(a, cc), dac = csubf(a, cc);
        float2 sbd = caddf(bb, dd), dbd = csubf(bb, dd);
        float2 idbd = make_float2(-dbd.y, dbd.x);
        v[K1]      = caddf(sac, sbd);
        v[K1 + 4]  = caddf(dac, idbd);
        v[K1 + 8]  = csubf(sac, sbd);
        v[K1 + 12] = csubf(dac, idbd);
    }
}

// z-twiddle: v[K1] *= e^{+2pi i q K1/256}
__device__ __forceinline__ void ztwiddle(float2* v, int q) {
    float ss, cc;
    sincos_rev((float)q * (1.0f / 256.0f), &ss, &cc);
    float2 w = make_float2(1.0f, 0.0f), stp = make_float2(cc, ss);
#pragma unroll
    for (int K1 = 0; K1 < 16; ++K1) {
        v[K1] = cmul(v[K1], w);
        w = cmul(w, stp);
    }
}

// ---------------- Kernel Q: partial chain product over stages 1..17 ----------------
__global__ __launch_bounds__(256) void build_q(const float* __restrict__ el,
                                               float2* __restrict__ Q) {
    __shared__ float c_s[18], s_s[18], T_s[18];
    int tid = threadIdx.x;
    if (tid < 18) {
        float e = el[tid];
        float shift1 = e * (1.0f / (float)(1u << tid));
        float sh2 = 1.0f - shift1;                        // THE float32 rounding
        float s = sh2 * (float)(1u << tid);
        float c = (float)(6.2831853071795864769 / (double)((1u << tid) + 1u));
        c_s[tid] = c;
        s_s[tid] = s;
        float p  = (float)(1u << tid) * c;
        float th = p * s;
        float sn, cs; phase_sincos(th, &sn, &cs);
        T_s[tid] = cs;
    }
    __syncthreads();

    unsigned r = blockIdx.x * 256u + (unsigned)tid;       // [0, 2^18)
    if (r == 0u) { Q[0] = make_float2(1.0f, 0.0f); return; }

    unsigned t = (unsigned)__builtin_ctz(r);              // t <= 17
    float Pr = T_s[t], Pi = 0.0f;

#pragma unroll
    for (int i = 1; i <= 17; ++i) {
        unsigned hi = 1u << i;
        int sd = (int)((r + hi) & (2u * hi - 1u)) - (int)hi;
        int K  = (i <= (int)t) ? 0 : (sd < 0 ? -sd : sd);
        float sgn = (sd < 0) ? -1.0f : 1.0f;
        float p  = (float)K * c_s[i];
        float th = p * s_s[i];
        float sn, cs; phase_sincos(th, &sn, &cs);
        float ssn = sgn * sn;
        float nr = Pr * cs - Pi * ssn;
        float ni = Pr * ssn + Pi * cs;
        Pr = nr; Pi = ni;
    }
    Q[r] = make_float2(Pr, Pi);
}

// ---------------- chain factor for stage i at bin k (exact float sequence) ----------------
__device__ __forceinline__ float2 cfac(int i, unsigned k, float ci, float si) {
    unsigned hi = 1u << i;
    int sd = (int)((k + hi) & (2u * hi - 1u)) - (int)hi;
    int K  = (sd < 0) ? -sd : sd;
    float sgn = (sd < 0) ? -1.0f : 1.0f;
    float th = ((float)K * ci) * si;
    float sn, cs; phase_sincos(th, &sn, &cs);
    return make_float2(cs, sgn * sn);
}

// ---------------- chain tail: level-24 factors + c2r pack ----------------
// ts/tc = sin/cos(2*pi*k/2^25), supplied by caller (recurrence or direct).
struct WPair { float2 wk, wmk; };

__device__ __forceinline__ WPair chain_tail(unsigned k, float Pr, float Pi,
                                            float c24, float s24,
                                            float ts, float tc) {
    const float sc = 1.0f / 33554432.0f;                  // 1/N
    unsigned mk = M24 - k;
    float thk = ((float)k  * c24) * s24;
    float thm = ((float)mk * c24) * s24;
    float snk, csk, snm, csm;
    phase_sincos(thk, &snk, &csk);
    phase_sincos(thm, &snm, &csm);

    float Skr = Pr * csk - Pi * snk;
    float Ski = Pr * snk + Pi * csk;
    float Smr = Pr * csm + Pi * snm;                      // conj(P) * e^{i*thm}
    float Smi = Pr * snm - Pi * csm;

    float Ar = Skr + Smr, Ai = Ski - Smi;
    float Br = Skr - Smr, Bi = Ski + Smi;
    float Cr = tc * Br - ts * Bi;
    float Ci = ts * Br + tc * Bi;

    WPair w;
    w.wk  = make_float2((Ar - Ci) * sc, (Ai + Cr) * sc);
    w.wmk = make_float2((Ar + Ci) * sc, (Cr - Ai) * sc);
    return w;
}

// ---------------- full chain (block-0 special rows only) ----------------
__device__ WPair chain_W_full(unsigned k, const float* __restrict__ el,
                              const float2* __restrict__ Q) {
    unsigned t = (unsigned)__builtin_ctz(k);              // t <= 23
    unsigned r = k & 0x3FFFFu;
    float Pr, Pi;
    if (r != 0u) {
        float2 q = Q[r];
        Pr = q.x; Pi = q.y;
    } else {
        float ct = c_of((int)t);
        float st = s_of(el, (int)t);
        float p  = (float)(1u << t) * ct;
        float th = p * st;
        float sn, cs; phase_sincos(th, &sn, &cs);
        Pr = cs; Pi = 0.0f;
    }
#pragma unroll
    for (int i = 18; i <= 23; ++i) {
        unsigned hi = 1u << i;
        int sd = (int)((k + hi) & (2u * hi - 1u)) - (int)hi;
        int K  = (i <= (int)t) ? 0 : (sd < 0 ? -sd : sd);
        float sgn = (sd < 0) ? -1.0f : 1.0f;
        float th = ((float)K * c_of(i)) * s_of(el, i);
        float sn, cs; phase_sincos(th, &sn, &cs);
        float ssn = sgn * sn;
        float nr = Pr * cs - Pi * ssn;
        float ni = Pr * ssn + Pi * cs;
        Pr = nr; Pi = ni;
    }
    float ts, tc;
    sincos_rev((float)k * (1.0f / 33554432.0f), &ts, &tc);
    return chain_tail(k, Pr, Pi, c_of(24), s_of(el, 24), ts, tc);
}

// ---------------- row -> column map (32-row mirror-closed block sets) ----------------
__device__ __forceinline__ int c_of_row32(int b, int r) {
    if (b == 0) {
        if (r < 16)  return r;              // 0..15
        if (r == 16) return 32768;          // self-mirrored
        return 65536 - (r - 16);            // r=17..31 -> 65535..65521
    }
    return (r < 16) ? (16 * b + r) : (65536 - 16 * b - (r - 16));
}

// ---------------- Fused: build W (LDS) + radix-16^2 IDFT over k3 ----------------
// 512 threads, 32 columns/block (16 consecutive + 16 mirror-consecutive),
// 2048 blocks. LDS: flat 64 KiB with per-row rotation (no padding).
__global__ __launch_bounds__(512, 4) void fused_build_fft_a(const float* __restrict__ el,
                                                            const float2* __restrict__ Q,
                                                            float2* __restrict__ out) {
    __shared__ float2 lds2[8192];                         // exactly 64 KiB
#define LA(r, c_) lds2[(((r) << 8)) | ((((c_) + (r)) & 255))]
    int tid = threadIdx.x;
    int b  = xcd_swizzle(blockIdx.x, 2048);
    int pr = tid & 15;                                    // pair-row 0..15
    int kq = tid >> 4;                                    // 0..31

    if (b == 0 && pr == 0) {
        // c=0 (row 0) and c=32768 (row 16): full chains, both self-mirrored.
        int rsp = (kq < 16) ? 0 : 16;
        int kql = kq & 15;
        unsigned cb = (rsp == 0) ? 0u : 32768u;
#pragma unroll 1
        for (int u = 0; u < 8; ++u) {
            int k3 = kql + 16 * u;                        // 0..127
            if (rsp == 0 && k3 == 0) {
                float c24 = c_of(24), s24v = s_of(el, 24);
                float th = (16777216.0f * c24) * s24v;
                float sn, cs; phase_sincos(th, &sn, &cs);
                const float sc = 1.0f / 33554432.0f;
                LA(0, 0) = make_float2((1.0f + cs) * sc, (1.0f - cs) * sc);
                WPair w = chain_W_full(8388608u, el, Q);
                LA(0, 128) = w.wk;
            } else {
                unsigned k = cb + ((unsigned)k3 << 16);
                WPair w = chain_W_full(k, el, Q);
                if (rsp == 0) { LA(0, k3)  = w.wk; LA(0, 256 - k3)  = w.wmk; }
                else          { LA(16, k3) = w.wk; LA(16, 255 - k3) = w.wmk; }
            }
        }
    } else {
        int c = (b == 0) ? pr : (16 * b + pr);            // low-side column (>=1)
        float s18 = s_of(el, 18), s19 = s_of(el, 19), s20 = s_of(el, 20),
              s21 = s_of(el, 21), s22 = s_of(el, 22), s23 = s_of(el, 23),
              s24v = s_of(el, 24);
        // k = kbase + u*2^21, u=0..7 ; k3 = kq + 32u
        unsigned kbase = (unsigned)c + ((unsigned)kq << 16);
        unsigned rres  = kbase & 0x3FFFFu;                // nonzero
        float2 P1 = Q[rres];
        P1 = cmul(P1, cfac(18, kbase, c_of(18), s18));    // const across u
        P1 = cmul(P1, cfac(19, kbase, c_of(19), s19));    // const across u
        P1 = cmul(P1, cfac(20, kbase, c_of(20), s20));    // const across u
        float2 P2[2], P3[4];
#pragma unroll
        for (int j = 0; j < 2; ++j)
            P2[j] = cmul(P1, cfac(21, kbase + ((unsigned)j << 21), c_of(21), s21));
#pragma unroll
        for (int j = 0; j < 4; ++j)
            P3[j] = cmul(P2[j & 1], cfac(22, kbase + ((unsigned)j << 21), c_of(22), s22));

        // c2r twiddle angle = (kbase + u*2^21)/2^25 rev: step is EXACTLY 1/16 rev
        // (22.5 deg) -> one sincos + exact rotation by cos/sin(pi/8) per u.
        const float RC = 0.92387953251128675613f;         // cos(pi/8)
        const float RS = 0.38268343236508977173f;         // sin(pi/8)
        float ts, tc;
        sincos_rev((float)kbase * (1.0f / 33554432.0f), &ts, &tc);

#pragma unroll 1
        for (int u = 0; u < 8; ++u) {
            int k3 = kq + 32 * u;
            unsigned k = kbase + ((unsigned)u << 21);
            float2 P = cmul(P3[u & 3], cfac(23, k, c_of(23), s23));
            WPair w = chain_tail(k, P.x, P.y, c_of(24), s24v, ts, tc);
            LA(pr, k3) = w.wk;
            LA(pr + 16, 255 - k3) = w.wmk;
            float nts = ts * RC + tc * RS;                // rotate +22.5 deg
            float ntc = tc * RC - ts * RS;
            ts = nts; tc = ntc;
        }
    }
    __syncthreads();

    // phase 1: thread (row, q) owns column-class q of row; row = tid&31, q = tid>>5
    int row = tid & 31;
    int q   = tid >> 5;                                   // 0..15
    float2 v[16];
#pragma unroll
    for (int n1 = 0; n1 < 16; ++n1) v[n1] = LA(row, q + 16 * n1);
    fft16_inv(v);
    ztwiddle(v, q);
#pragma unroll
    for (int K1 = 0; K1 < 16; ++K1) LA(row, K1 * 16 + q) = v[K1];  // own slot set
    __syncthreads();

    // phase 2: thread (row, q) owns K1=q; output t3 = q + 16*K2 (natural order)
#pragma unroll
    for (int n2 = 0; n2 < 16; ++n2) v[n2] = LA(row, q * 16 + n2);
    fft16_inv(v);
    int cr = c_of_row32(b, row);
#pragma unroll
    for (int K2 = 0; K2 < 16; ++K2)
        out[cr + ((q + 16 * K2) << 16)] = v[K2];
#undef LA
}

// ---------------- Stage B: twiddle + radix-16^2 IDFT over k2 (stride 256) ----------------
__global__ __launch_bounds__(256, 4) void fft_stage_b(const float2* __restrict__ in,
                                                      float2* __restrict__ out) {
    __shared__ float2 lds[16][257];
    int tid = threadIdx.x;
    int wg  = xcd_swizzle(blockIdx.x, 4096);
    int k1b = (wg & 15) * 16;
    int t3  = wg >> 4;
    int row = tid & 15;
    int q   = tid >> 4;                                   // n2 = q; loads ARE the phase-1 set

    float2 v[16];
    const float2* src = in + (k1b + row + (q << 8) + (t3 << 16));
#pragma unroll
    for (int u = 0; u < 16; ++u) v[u] = src[u << 12];     // k2 = q + 16u

    {   // inter-stage twiddle e^{+2pi i t3 k2 / 65536}
        float sb, cb; sincos_rev((float)(t3 * q)  * (1.0f / 65536.0f), &sb, &cb);
        float ssx, csx; sincos_rev((float)t3 * (1.0f / 4096.0f), &ssx, &csx);
        float2 w = make_float2(cb, sb), stp = make_float2(csx, ssx);
#pragma unroll
        for (int u = 0; u < 16; ++u) {
            v[u] = cmul(v[u], w);
            w = cmul(w, stp);
        }
    }
    fft16_inv(v);
    ztwiddle(v, q);
#pragma unroll
    for (int K1 = 0; K1 < 16; ++K1) lds[row][K1 * 16 + q] = v[K1];
    __syncthreads();

#pragma unroll
    for (int n2 = 0; n2 < 16; ++n2) v[n2] = lds[row][q * 16 + n2];
    fft16_inv(v);
#pragma unroll
    for (int K2 = 0; K2 < 16; ++K2)
        out[k1b + row + ((q + 16 * K2) << 8) + (t3 << 16)] = v[K2];
}

// ---------------- Stage C: twiddle + radix-16^2 IDFT over k1 (stride 1) ----------------
__global__ __launch_bounds__(256, 4) void fft_stage_c(const float2* __restrict__ in,
                                                      float2* __restrict__ out) {
    __shared__ float2 lds[16][257];
    int tid = threadIdx.x;
    int wg  = xcd_swizzle(blockIdx.x, 4096);
    int t3b = (wg & 15) * 16;
    int t2  = wg >> 4;

    {   // load one k1 column across 16 rows, twiddle, raw-stage to LDS
        int k1 = tid;
        const float2* src = in + (k1 + (t2 << 8) + (t3b << 16));
        float2 vb[16];
#pragma unroll
        for (int u = 0; u < 16; ++u) vb[u] = src[u << 16];
        int base = (t3b + (t2 << 8)) * k1;                // < 2^24, exact in float
        float sb, cb; sincos_rev((float)base * (1.0f / 16777216.0f), &sb, &cb);
        float ssx, csx; sincos_rev((float)k1 * (1.0f / 1048576.0f), &ssx, &csx);  // 16/2^24
        float2 w = make_float2(cb, sb), stp = make_float2(csx, ssx);
#pragma unroll
        for (int u = 0; u < 16; ++u) {
            lds[u][k1] = cmul(vb[u], w);
            w = cmul(w, stp);
        }
    }
    __syncthreads();

    int rr = tid & 15;
    int q  = tid >> 4;
    float2 v[16];
#pragma unroll
    for (int n1 = 0; n1 < 16; ++n1) v[n1] = lds[rr][q + 16 * n1];
    fft16_inv(v);
    ztwiddle(v, q);
#pragma unroll
    for (int K1 = 0; K1 < 16; ++K1) lds[rr][K1 * 16 + q] = v[K1];  // own slot set
    __syncthreads();

#pragma unroll
    for (int n2 = 0; n2 < 16; ++n2) v[n2] = lds[rr][q * 16 + n2];
    fft16_inv(v);
#pragma unroll
    for (int K2 = 0; K2 < 16; ++K2)
        out[(t3b + rr) + (t2 << 8) + ((q + 16 * K2) << 16)] = v[K2];
}

extern "C" void kernel_launch(void* const* d_in, const int* in_sizes, int n_in,
                              void* d_out, int out_size, void* d_ws, size_t ws_size,
                              hipStream_t stream) {
    const float* el = (const float*)d_in[0];   // 25 floats
    float2* Gd = (float2*)d_out;               // out buffer doubles as complex ping-pong
    float2* Q  = (float2*)d_ws;                // Q table (2 MiB) lives in ws until stage B

    // build_q (ws) -> fusedA: (chains+FFT) -> out -> stageB: out->ws (clobbers Q, ok)
    // -> stageC: ws->out (final real signal)
    hipLaunchKernelGGL(build_q,           dim3(1024), dim3(256), 0, stream, el, Q);
    hipLaunchKernelGGL(fused_build_fft_a, dim3(2048), dim3(512), 0, stream, el, Q, Gd);
    hipLaunchKernelGGL(fft_stage_b,       dim3(4096), dim3(256), 0, stream, Gd, (float2*)d_ws);
    hipLaunchKernelGGL(fft_stage_c,       dim3(4096), dim3(256), 0, stream, (float2*)d_ws, Gd);
}